// Round 9
// baseline (2332.551 us; speedup 1.0000x reference)
//
#include <hip/hip_runtime.h>
#include <cstdint>
#include <cstddef>

// Problem constants
#define NBATCH 128
#define NTIME  512
#define NIN    64
#define NHID   256
#define NG     768     // 3*H
#define NLAT   32
#define NPp    16      // P
#define NPI    48
#define NOD    8
#define NPAR   1056
#define MEAN_OFF 0
#define STD_OFF  524288      // B*T*OD
#define HT_OFF   1048576     // 2*B*T*OD

typedef _Float16 f16;
typedef _Float16 f16x2 __attribute__((ext_vector_type(2)));
typedef _Float16 f16x8 __attribute__((ext_vector_type(8)));
typedef float    f32x4 __attribute__((ext_vector_type(4)));
typedef uint32_t u32;

static __device__ __forceinline__ f16x2 u2h(u32 u) {
  union { u32 u; f16x2 h; } x; x.u = u; return x.h;
}
static __device__ __forceinline__ f16x8 cvt8(float4 a, float4 b) {
  f16x8 r;
  r[0] = (f16)a.x; r[1] = (f16)a.y; r[2] = (f16)a.z; r[3] = (f16)a.w;
  r[4] = (f16)b.x; r[5] = (f16)b.y; r[6] = (f16)b.z; r[7] = (f16)b.w;
  return r;
}

static __device__ __forceinline__ float fdot2(f16x2 a, f16x2 b, float c) {
#if __has_builtin(__builtin_amdgcn_fdot2)
  return __builtin_amdgcn_fdot2(a, b, c, false);   // v_dot2_f32_f16
#else
  return c + (float)a.x * (float)b.x + (float)a.y * (float)b.y;
#endif
}
static __device__ __forceinline__ float fexp2(float x) {
#if __has_builtin(__builtin_amdgcn_exp2f)
  return __builtin_amdgcn_exp2f(x);
#else
  return exp2f(x);
#endif
}
static __device__ __forceinline__ float frcp(float x) {
#if __has_builtin(__builtin_amdgcn_rcpf)
  return __builtin_amdgcn_rcpf(x);
#else
  return 1.0f / x;
#endif
}
static __device__ __forceinline__ float fsigmoid(float x) {
  return frcp(1.0f + fexp2(-1.4426950408889634f * x));
}
static __device__ __forceinline__ float ftanh(float x) {
  return 1.0f - 2.0f * frcp(1.0f + fexp2(2.8853900817779268f * x));
}
static __device__ __forceinline__ float fexpf_(float x) {
  return fexp2(1.4426950408889634f * x);
}

// ---------------------------------------------------------------------------
// K1: gx[m, n] = sum_k x[m,k] * w_ih[n,k] + b_ih[n]   (M=65536, N=768, K=64)
// ---------------------------------------------------------------------------
__global__ __launch_bounds__(256, 1) void k_gx(
    const float* __restrict__ x, const float* __restrict__ w_ih,
    const float* __restrict__ b_ih, f16* __restrict__ gx)
{
  __shared__ f16x2 xs[64 * 33];
  __shared__ f16x2 ws[192 * 33];
  __shared__ float bs[192];
  const int tid = threadIdx.x;
  const int m0 = blockIdx.x * 64;
  const int c0 = blockIdx.y * 192;
  const float2* x2 = (const float2*)x;
  const float2* w2 = (const float2*)w_ih;
  for (int idx = tid; idx < 64 * 32; idx += 256) {
    int r = idx >> 5, kk = idx & 31;
    float2 v = x2[(size_t)(m0 + r) * 32 + kk];
    xs[r * 33 + kk] = f16x2{(f16)v.x, (f16)v.y};
  }
  for (int idx = tid; idx < 192 * 32; idx += 256) {
    int r = idx >> 5, kk = idx & 31;
    float2 v = w2[(size_t)(c0 + r) * 32 + kk];
    ws[r * 33 + kk] = f16x2{(f16)v.x, (f16)v.y};
  }
  if (tid < 192) bs[tid] = b_ih[c0 + tid];
  __syncthreads();

  const int tc = tid & 15;
  const int tr = tid >> 4;
  float acc[4][12];
  #pragma unroll
  for (int j = 0; j < 4; ++j)
    #pragma unroll
    for (int i = 0; i < 12; ++i) acc[j][i] = 0.f;

  for (int kk = 0; kk < 32; ++kk) {
    f16x2 xa[4], wb[12];
    #pragma unroll
    for (int j = 0; j < 4; ++j) xa[j] = xs[(tr * 4 + j) * 33 + kk];
    #pragma unroll
    for (int i = 0; i < 12; ++i) wb[i] = ws[(tc * 12 + i) * 33 + kk];
    #pragma unroll
    for (int j = 0; j < 4; ++j)
      #pragma unroll
      for (int i = 0; i < 12; ++i) acc[j][i] = fdot2(xa[j], wb[i], acc[j][i]);
  }

  f16x2* g2 = (f16x2*)gx;
  #pragma unroll
  for (int j = 0; j < 4; ++j) {
    size_t row = (size_t)(m0 + tr * 4 + j);
    #pragma unroll
    for (int i2 = 0; i2 < 6; ++i2) {
      float a0 = acc[j][2 * i2]     + bs[tc * 12 + 2 * i2];
      float a1 = acc[j][2 * i2 + 1] + bs[tc * 12 + 2 * i2 + 1];
      g2[row * 384 + (size_t)(c0 / 2) + tc * 6 + i2] = f16x2{(f16)a0, (f16)a1};
    }
  }
}

// ---------------------------------------------------------------------------
// K2 v10: MFMA GRU scan. Why MFMA: the toolchain caps arch VGPRs at 128 for
// VALU-only kernels (R1-R8 invariant; every weight-resident dot2 design
// spilled). MFMA operands may live in AGPRs (gfx950 unified file; m98 shows
// 164V+64A allocated) -> the only way to make 384 KB/block of weights
// register-resident. M=16 batches/block, 8 blocks, 8 waves/block.
// Wave w: units [32w,32w+32) x 3 gates = 6 N-tiles x 8 K-tiles = 48
// B-fragments (f16x8). Per step: 8 A-fragments from LDS (m120-verified
// A[m=lane&15][k=quad*8+j]) x 6 MFMAs each; C-layout gates
// (batch=quad*4+reg, unit=lane&15 -- m89-verified); gx gathered per-lane;
// ONE barrier/step via double-buffered h.
// ---------------------------------------------------------------------------
#define MF __builtin_amdgcn_mfma_f32_16x16x32_f16
#define LDP 264   // halves per h-row: 16B-aligned rows, conflict-padded

#define DECL_FRAGS(P) f16x8 P##0, P##1, P##2, P##3, P##4, P##5, P##6, P##7
#define LOAD_FRAGS(P, row) { \
  const float4* pr = (const float4*)(w_hh + (size_t)(row) * 256) + (q << 1); \
  P##0 = cvt8(pr[0],  pr[1]); \
  P##1 = cvt8(pr[8],  pr[9]); \
  P##2 = cvt8(pr[16], pr[17]); \
  P##3 = cvt8(pr[24], pr[25]); \
  P##4 = cvt8(pr[32], pr[33]); \
  P##5 = cvt8(pr[40], pr[41]); \
  P##6 = cvt8(pr[48], pr[49]); \
  P##7 = cvt8(pr[56], pr[57]); }

#define KSTEP(kt) { \
  f16x8 A = *(const f16x8*)(hc + kt * 32); \
  c00 = MF(A, B00_##kt, c00, 0, 0, 0); \
  c01 = MF(A, B01_##kt, c01, 0, 0, 0); \
  c10 = MF(A, B10_##kt, c10, 0, 0, 0); \
  c11 = MF(A, B11_##kt, c11, 0, 0, 0); \
  c20 = MF(A, B20_##kt, c20, 0, 0, 0); \
  c21 = MF(A, B21_##kt, c21, 0, 0, 0); }

// gate math for (s, r): CR/CZ/CN = accum vectors, X* = gx f16, HP = h state
#define GATE(rr_, s, CR, CZ, CN, XR, XZ, XN, HP) { \
  float g_r = fsigmoid(CR[rr_] + bhr##s + (float)XR); \
  float g_z = fsigmoid(CZ[rr_] + bhz##s + (float)XZ); \
  float g_n = ftanh((float)XN + g_r * (CN[rr_] + bhn##s)); \
  HP = (1.0f - g_z) * g_n + g_z * HP; \
  f16 hv = (f16)HP; \
  hw[(q * 4 + rr_) * LDP + s * 16] = hv; \
  rnn_t[(size_t)(q * 4 + rr_) * (512 * 256) + s * 16] = hv; }

__global__ __launch_bounds__(512, 1) void k_scan(
    const float* __restrict__ hidden, const float* __restrict__ w_hh,
    const float* __restrict__ b_hh, const f16* __restrict__ gx,
    f16* __restrict__ rnn, float* __restrict__ out)
{
  __shared__ __align__(16) f16 hbuf[2][16 * LDP];   // double-buffered h
  const int tid = threadIdx.x;
  const int lane = tid & 63;
  const int w = tid >> 6;          // wave 0..7 -> units [32w, 32w+32)
  const int nc = lane & 15;        // fragment col / A row
  const int q  = lane >> 4;        // quad
  const int b0 = blockIdx.x * 16;  // batch tile
  const int u0 = w * 32 + nc;      // unit for s=0 (s=1: +16)

  // --- 48 stationary B-fragments (w_hh rows: g*256 + unit) ---
  DECL_FRAGS(B00_); DECL_FRAGS(B01_);   // r gate, s=0/1
  DECL_FRAGS(B10_); DECL_FRAGS(B11_);   // z gate
  DECL_FRAGS(B20_); DECL_FRAGS(B21_);   // n gate
  LOAD_FRAGS(B00_, u0);
  LOAD_FRAGS(B01_, u0 + 16);
  LOAD_FRAGS(B10_, 256 + u0);
  LOAD_FRAGS(B11_, 256 + u0 + 16);
  LOAD_FRAGS(B20_, 512 + u0);
  LOAD_FRAGS(B21_, 512 + u0 + 16);

  // --- biases (per lane: its 2 units x 3 gates) ---
  const float bhr0 = b_hh[u0],       bhr1 = b_hh[u0 + 16];
  const float bhz0 = b_hh[256 + u0], bhz1 = b_hh[256 + u0 + 16];
  const float bhn0 = b_hh[512 + u0], bhn1 = b_hh[512 + u0 + 16];

  // --- h state: this lane owns (batch q*4+r, units u0, u0+16) ---
  float hp00 = hidden[(b0 + q * 4 + 0) * 256 + u0];
  float hp01 = hidden[(b0 + q * 4 + 1) * 256 + u0];
  float hp02 = hidden[(b0 + q * 4 + 2) * 256 + u0];
  float hp03 = hidden[(b0 + q * 4 + 3) * 256 + u0];
  float hp10 = hidden[(b0 + q * 4 + 0) * 256 + u0 + 16];
  float hp11 = hidden[(b0 + q * 4 + 1) * 256 + u0 + 16];
  float hp12 = hidden[(b0 + q * 4 + 2) * 256 + u0 + 16];
  float hp13 = hidden[(b0 + q * 4 + 3) * 256 + u0 + 16];
  {
    f16* h0p = &hbuf[0][w * 32 + nc];
    h0p[(q * 4 + 0) * LDP]      = (f16)hp00;
    h0p[(q * 4 + 1) * LDP]      = (f16)hp01;
    h0p[(q * 4 + 2) * LDP]      = (f16)hp02;
    h0p[(q * 4 + 3) * LDP]      = (f16)hp03;
    h0p[(q * 4 + 0) * LDP + 16] = (f16)hp10;
    h0p[(q * 4 + 1) * LDP + 16] = (f16)hp11;
    h0p[(q * 4 + 2) * LDP + 16] = (f16)hp12;
    h0p[(q * 4 + 3) * LDP + 16] = (f16)hp13;
  }

  // gx gather bases: row (b0+q*4+r), col base (w*32 + nc); offsets g*256+s*16
  const f16* gb0 = gx + ((size_t)(b0 + q * 4 + 0) * 512) * 768 + w * 32 + nc;
  const f16* gb1 = gx + ((size_t)(b0 + q * 4 + 1) * 512) * 768 + w * 32 + nc;
  const f16* gb2 = gx + ((size_t)(b0 + q * 4 + 2) * 512) * 768 + w * 32 + nc;
  const f16* gb3 = gx + ((size_t)(b0 + q * 4 + 3) * 512) * 768 + w * 32 + nc;

  f16* rnn_b = rnn + ((size_t)b0 * 512) * 256 + w * 32 + nc;   // + r*512*256 + t*256 + s*16
  __syncthreads();

  #pragma unroll 2
  for (int t = 0; t < NTIME; ++t) {
    // --- issue gx gathers for this step (consumed after MFMA phase) ---
    const f16* g0 = gb0 + (size_t)t * 768;
    const f16* g1 = gb1 + (size_t)t * 768;
    const f16* g2 = gb2 + (size_t)t * 768;
    const f16* g3 = gb3 + (size_t)t * 768;
    f16 x000 = g0[0],   x010 = g0[16];
    f16 x100 = g0[256], x110 = g0[272];
    f16 x200 = g0[512], x210 = g0[528];
    f16 x001 = g1[0],   x011 = g1[16];
    f16 x101 = g1[256], x111 = g1[272];
    f16 x201 = g1[512], x211 = g1[528];
    f16 x002 = g2[0],   x012 = g2[16];
    f16 x102 = g2[256], x112 = g2[272];
    f16 x202 = g2[512], x212 = g2[528];
    f16 x003 = g3[0],   x013 = g3[16];
    f16 x103 = g3[256], x113 = g3[272];
    f16 x203 = g3[512], x213 = g3[528];

    // --- MFMA phase: D = h(16x256) @ W^T slice ---
    const f16* hc = &hbuf[t & 1][nc * LDP + q * 8];
    f32x4 c00 = {0.f, 0.f, 0.f, 0.f}, c01 = {0.f, 0.f, 0.f, 0.f};
    f32x4 c10 = {0.f, 0.f, 0.f, 0.f}, c11 = {0.f, 0.f, 0.f, 0.f};
    f32x4 c20 = {0.f, 0.f, 0.f, 0.f}, c21 = {0.f, 0.f, 0.f, 0.f};
    KSTEP(0) KSTEP(1) KSTEP(2) KSTEP(3)
    KSTEP(4) KSTEP(5) KSTEP(6) KSTEP(7)

    // --- gate phase (C layout: batch = q*4+reg, unit col = nc) ---
    f16* hw = &hbuf[(t + 1) & 1][w * 32 + nc];
    f16* rnn_t = rnn_b + (size_t)t * 256;
    GATE(0, 0, c00, c10, c20, x000, x100, x200, hp00)
    GATE(1, 0, c00, c10, c20, x001, x101, x201, hp01)
    GATE(2, 0, c00, c10, c20, x002, x102, x202, hp02)
    GATE(3, 0, c00, c10, c20, x003, x103, x203, hp03)
    GATE(0, 1, c01, c11, c21, x010, x110, x210, hp10)
    GATE(1, 1, c01, c11, c21, x011, x111, x211, hp11)
    GATE(2, 1, c01, c11, c21, x012, x112, x212, hp12)
    GATE(3, 1, c01, c11, c21, x013, x113, x213, hp13)
    __syncthreads();
  }

  // --- final hidden state (fp32) ---
  float* op = out + HT_OFF + (size_t)(b0 + q * 4) * 256 + u0;
  op[0 * 256]      = hp00;
  op[1 * 256]      = hp01;
  op[2 * 256]      = hp02;
  op[3 * 256]      = hp03;
  op[0 * 256 + 16] = hp10;
  op[1 * 256 + 16] = hp11;
  op[2 * 256 + 16] = hp12;
  op[3 * 256 + 16] = hp13;
}

// ---------------------------------------------------------------------------
// K3 helper: half-row dot (16 of 32 latents; caller pre-offset wb by kh*2
// uint4 and t8 = te2 + kh*8). init carries b_par[row] on kh==0 only.
// ---------------------------------------------------------------------------
static __device__ __forceinline__ float rowdot_h(const uint4* __restrict__ wb,
                                                 const f16x2* __restrict__ t8,
                                                 int r, float init)
{
  uint4 v0 = wb[r * 4];
  uint4 v1 = wb[r * 4 + 1];
  float a0 = init, a1 = 0.f, a2 = 0.f, a3 = 0.f;
  a0 = fdot2(u2h(v0.x), t8[0], a0);
  a1 = fdot2(u2h(v0.y), t8[1], a1);
  a2 = fdot2(u2h(v0.z), t8[2], a2);
  a3 = fdot2(u2h(v0.w), t8[3], a3);
  a0 = fdot2(u2h(v1.x), t8[4], a0);
  a1 = fdot2(u2h(v1.y), t8[5], a1);
  a2 = fdot2(u2h(v1.z), t8[6], a2);
  a3 = fdot2(u2h(v1.w), t8[7], a3);
  return (a0 + a1) + (a2 + a3);
}

// ---------------------------------------------------------------------------
// K3 v5: head, 2 threads per (b,t) row. launch_bounds(256,1) -> full reg
// budget so te[]/vh[]/oh[] stay resident.
// ---------------------------------------------------------------------------
#define HEAD_T 256
__global__ __launch_bounds__(HEAD_T, 1) void k_head(
    const float* __restrict__ x, const float* __restrict__ w_lat,
    const float* __restrict__ b_lat, const float* __restrict__ w_par,
    const float* __restrict__ b_par, const f16* __restrict__ rnn,
    float* __restrict__ out)
{
  __shared__ __align__(16) f16x2 buf[384 * 16];   // 24 KB chunk buffer
  const int tid = threadIdx.x;
  const int j = tid >> 1, kh = tid & 1;
  const size_t m = (size_t)blockIdx.x * (HEAD_T / 2) + j;

  // ---- phase A: te = b_lat + w_lat @ h  (K split by kh)
  const float2* wl2 = (const float2*)w_lat;
  for (int idx = tid; idx < 32 * 128; idx += HEAD_T) {
    float2 v = wl2[idx];
    buf[idx] = f16x2{(f16)v.x, (f16)v.y};
  }
  __syncthreads();

  float te[32];
  #pragma unroll
  for (int c = 0; c < 32; ++c) te[c] = kh ? 0.f : b_lat[c];
  const uint4* hrow = (const uint4*)(rnn + m * NHID) + kh * 16;
  const uint4* wl4 = (const uint4*)buf;    // 32 uint4 per 256-wide row
  #pragma unroll 2
  for (int c4 = 0; c4 < 16; ++c4) {
    uint4 hv = hrow[c4];
    f16x2 hx0 = u2h(hv.x), hx1 = u2h(hv.y), hx2 = u2h(hv.z), hx3 = u2h(hv.w);
    #pragma unroll
    for (int c = 0; c < 32; ++c) {
      uint4 wv = wl4[c * 32 + kh * 16 + c4];
      te[c] = fdot2(u2h(wv.x), hx0, te[c]);
      te[c] = fdot2(u2h(wv.y), hx1, te[c]);
      te[c] = fdot2(u2h(wv.z), hx2, te[c]);
      te[c] = fdot2(u2h(wv.w), hx3, te[c]);
    }
  }
  #pragma unroll
  for (int c = 0; c < 32; ++c) te[c] += __shfl_xor(te[c], 1, 64);
  f16x2 te2[16];
  #pragma unroll
  for (int k = 0; k < 16; ++k) te2[k] = f16x2{(f16)te[2 * k], (f16)te[2 * k + 1]};
  const f16x2* t8 = te2 + kh * 8;
  __syncthreads();

  const float2* wp2 = (const float2*)w_par;   // 16 float2 per 32-wide row
  const uint4* wb = ((const uint4*)buf) + kh * 2;
  const float* xrow = x + m * NIN;
  float vh[16];
  #pragma unroll
  for (int p = 0; p < 16; ++p) vh[p] = 0.f;

  // ---- phase B0: w_h rows [0,384)  (p = 0..7)
  for (int idx = tid; idx < 384 * 16; idx += HEAD_T) {
    float2 v = wp2[idx];
    buf[idx] = f16x2{(f16)v.x, (f16)v.y};
  }
  __syncthreads();
  for (int i = 0; i < NPI; ++i) {
    float xi = xrow[i];
    #pragma unroll
    for (int p = 0; p < 8; ++p) {
      int row = p * NPI + i;
      float wv = rowdot_h(wb, t8, row, kh ? 0.f : b_par[row]);
      vh[p] += wv * xi;
    }
  }
  __syncthreads();

  // ---- phase B1: w_h rows [384,768)  (p = 8..15)
  for (int idx = tid; idx < 384 * 16; idx += HEAD_T) {
    float2 v = wp2[384 * 16 + idx];
    buf[idx] = f16x2{(f16)v.x, (f16)v.y};
  }
  __syncthreads();
  for (int i = 0; i < NPI; ++i) {
    float xi = xrow[i];
    #pragma unroll
    for (int p = 8; p < 16; ++p) {
      int row = p * NPI + i;
      float wv = rowdot_h(wb, t8, row - 384, kh ? 0.f : b_par[row]);
      vh[p] += wv * xi;
    }
  }
  __syncthreads();

  // ---- phase C: rows [768,1056) = b_h(16) + w_o(256) + b_o(16), 18 KB
  for (int idx = tid; idx < 288 * 16; idx += HEAD_T) {
    float2 v = wp2[768 * 16 + idx];
    buf[idx] = f16x2{(f16)v.x, (f16)v.y};
  }
  __syncthreads();

  float oh[16];
  #pragma unroll
  for (int p = 0; p < 16; ++p) {
    float bh = rowdot_h(wb, t8, p, kh ? 0.f : b_par[768 + p]);   // local row p
    float s = vh[p] + bh;
    s += __shfl_xor(s, 1, 64);
    oh[p] = ftanh(s);
  }

  #pragma unroll 2
  for (int o = 0; o < 16; ++o) {
    // b_o: local rows 272..288
    float macc = rowdot_h(wb, t8, 272 + o, kh ? 0.f : b_par[1040 + o]);
    #pragma unroll
    for (int p = 0; p < 16; ++p) {
      int grow = 784 + o * 16 + p;           // local 16 + o*16 + p
      float wv = rowdot_h(wb, t8, 16 + o * 16 + p, kh ? 0.f : b_par[grow]);
      macc += wv * oh[p];
    }
    macc += __shfl_xor(macc, 1, 64);
    if (!kh) {
      if (o < NOD) out[MEAN_OFF + m * NOD + o] = macc;
      else         out[STD_OFF + m * NOD + (o - NOD)] = fexpf_(macc);
    }
  }
}

// ---------------------------------------------------------------------------
extern "C" void kernel_launch(void* const* d_in, const int* in_sizes, int n_in,
                              void* d_out, int out_size, void* d_ws, size_t ws_size,
                              hipStream_t stream)
{
  const float* x      = (const float*)d_in[0];
  const float* hidden = (const float*)d_in[1];
  const float* w_ih   = (const float*)d_in[2];
  const float* w_hh   = (const float*)d_in[3];
  const float* b_ih   = (const float*)d_in[4];
  const float* b_hh   = (const float*)d_in[5];
  const float* w_lat  = (const float*)d_in[6];
  const float* b_lat  = (const float*)d_in[7];
  const float* w_par  = (const float*)d_in[8];
  const float* b_par  = (const float*)d_in[9];
  float* out = (float*)d_out;

  f16* gx  = (f16*)d_ws;                                  // 100,663,296 B
  f16* rnn = (f16*)((char*)d_ws + 100663296);             // 33,554,432 B

  k_gx  <<<dim3(1024, 4), 256, 0, stream>>>(x, w_ih, b_ih, gx);
  k_scan<<<NBATCH / 16, 512, 0, stream>>>(hidden, w_hh, b_hh, gx, rnn, out);
  k_head<<<512, HEAD_T, 0, stream>>>(x, w_lat, b_lat, w_par, b_par, rnn, out);
}